// Round 4
// baseline (160.456 us; speedup 1.0000x reference)
//
#include <hip/hip_runtime.h>
#include <stdint.h>

#define NIMG     128
#define NPROP    2000
#define NGT      100
#define NALL     2100   // NPROP + NGT (divisible by 4)
#define NALL4    (NALL / 4)
#define NSAMPLE  512
#define MAXPOS   128
#define NNEG     384
#define NCHUNK   9      // 9*256 = 2304 >= 2100

#define SAMP_OFF  (NIMG * NSAMPLE * 4)            // 262144
#define MATCH_OFF (SAMP_OFF + NIMG * NSAMPLE)     // 327680

// ws layout (u32): maskarg[NIMG*NALL] | rank[NIMG*NALL]

// ---------- kernel A: fused IoU mask/argmax + rank-by-counting ----------
__global__ __launch_bounds__(256) void prep_kernel(
    const float* __restrict__ rois, const float* __restrict__ scores,
    const float* __restrict__ gts, const float* __restrict__ rnd,
    unsigned int* __restrict__ maskarg, unsigned int* __restrict__ rank)
{
    __shared__ float s_gt[NGT * 4];
    __shared__ float s_ga[NGT];
    __shared__ __align__(16) unsigned int s_bits[NALL];
    const int img = blockIdx.y;
    const int tid = threadIdx.x;
    const int i = blockIdx.x * 256 + tid;

    for (int t = tid; t < NGT * 4; t += 256)
        s_gt[t] = gts[(size_t)img * NGT * 4 + t];
    for (int t = tid; t < NALL; t += 256)
        s_bits[t] = __float_as_uint(rnd[(size_t)img * NALL + t]);
    __syncthreads();
    for (int g = tid; g < NGT; g += 256) {
        float w = fmaxf(s_gt[g * 4 + 2] - s_gt[g * 4 + 0], 0.0f);
        float h = fmaxf(s_gt[g * 4 + 3] - s_gt[g * 4 + 1], 0.0f);
        s_ga[g] = w * h;
    }
    __syncthreads();

    if (i >= NALL) return;

    // ---- IoU -> mask / argmax ----
    float x0, y0, x1, y1, sc;
    if (i < NPROP) {
        const float* p = rois + ((size_t)img * NPROP + i) * 4;
        x0 = p[0]; y0 = p[1]; x1 = p[2]; y1 = p[3];
        sc = scores[(size_t)img * NPROP + i];
    } else {
        int g = i - NPROP;
        x0 = s_gt[g * 4 + 0]; y0 = s_gt[g * 4 + 1];
        x1 = s_gt[g * 4 + 2]; y1 = s_gt[g * 4 + 3];
        sc = 1.0f;
    }
    float aw = fmaxf(x1 - x0, 0.0f);
    float ah = fmaxf(y1 - y0, 0.0f);
    float area_a = aw * ah;
    float best = -1.0f;
    int barg = 0;
    for (int g = 0; g < NGT; ++g) {
        float tlx = fmaxf(x0, s_gt[g * 4 + 0]);
        float tly = fmaxf(y0, s_gt[g * 4 + 1]);
        float brx = fminf(x1, s_gt[g * 4 + 2]);
        float bry = fminf(y1, s_gt[g * 4 + 3]);
        float iw = fmaxf(brx - tlx, 0.0f);
        float ih = fmaxf(bry - tly, 0.0f);
        float inter = iw * ih;
        float uni = area_a + s_ga[g] - inter;
        float iou = (uni > 0.0f) ? (inter / uni) : 0.0f;
        if (iou > best) { best = iou; barg = g; }   // first-max tie-break
    }
    unsigned int m = 2;
    if (sc < 0.0f) m = 0;
    if (best >= 0.5f) m = 3;   // overrides score<0, per reference order
    maskarg[(size_t)img * NALL + i] = (m << 8) | (unsigned int)barg;

    // ---- rank = #{j : (bits_j, j) < (bits_i, i)}  (stable argsort position) ----
    const unsigned long long my64 =
        ((unsigned long long)s_bits[i] << 32) | (unsigned int)i;
    const uint4* k4 = reinterpret_cast<const uint4*>(s_bits);
    int cnt = 0;
    #pragma unroll 2
    for (int t = 0; t < NALL4; ++t) {           // ds_read_b128 broadcast, conflict-free
        uint4 v = k4[t];
        unsigned int j = (unsigned int)(t * 4);
        cnt += (((unsigned long long)v.x << 32) | (j + 0)) < my64;
        cnt += (((unsigned long long)v.y << 32) | (j + 1)) < my64;
        cnt += (((unsigned long long)v.z << 32) | (j + 2)) < my64;
        cnt += (((unsigned long long)v.w << 32) | (j + 3)) < my64;
    }
    rank[(size_t)img * NALL + i] = (unsigned int)cnt;
}

// ---------- kernel B: permute + dual stable selection ----------
#define CTHREADS 1024
#define NWAVES   (CTHREADS / 64)
__global__ __launch_bounds__(CTHREADS) void select_kernel(
    const float* __restrict__ rois, const float* __restrict__ gts,
    const unsigned int* __restrict__ maskarg, const unsigned int* __restrict__ rank,
    float* __restrict__ out)
{
    __shared__ unsigned short s_perm[NALL];
    __shared__ unsigned char s_mask[NALL];
    __shared__ unsigned char s_argb[NALL];
    __shared__ float s_gt[NGT * 4];
    __shared__ int w0[NWAVES], w1[NWAVES], w2[NWAVES];

    const int img  = blockIdx.x;
    const int tid  = threadIdx.x;
    const int wid  = tid >> 6;
    const int lane = tid & 63;

    for (int t = tid; t < NGT * 4; t += CTHREADS)
        s_gt[t] = gts[(size_t)img * NGT * 4 + t];
    for (int t = tid; t < NALL; t += CTHREADS) {
        unsigned int ma = maskarg[(size_t)img * NALL + t];
        s_mask[t] = (unsigned char)(ma >> 8);
        s_argb[t] = (unsigned char)(ma & 0xFF);
        unsigned int r = rank[(size_t)img * NALL + t];
        s_perm[r] = (unsigned short)t;
    }
    __syncthreads();

    for (int phase = 0; phase < 2; ++phase) {
        // phase 0: top-128 over [0,NALL), prio 3 > 2 > 0
        // phase 1: bot-384 over [MAXPOS,NALL), prio 2 > 3 > 0
        const int C     = phase ? 2 : 3;
        const int base  = phase ? MAXPOS : 0;
        const int limit = phase ? NNEG : MAXPOS;
        const int oofs  = phase ? MAXPOS : 0;
        const unsigned char hi = phase ? 2 : 3;   // highest-priority mask value
        const unsigned char mid = phase ? 3 : 2;

        int p0 = base + tid * C;
        int p1 = min(p0 + C, NALL);
        int c0 = 0, c1 = 0, c2 = 0;
        for (int p = p0; p < p1; ++p) {
            unsigned char m = s_mask[s_perm[p]];
            if (m == hi) ++c0; else if (m == mid) ++c1; else ++c2;
        }
        // wave-level inclusive scans (no barriers)
        int s0 = c0, s1 = c1, s2 = c2;
        for (int d = 1; d < 64; d <<= 1) {
            int t0 = __shfl_up(s0, d);
            int t1 = __shfl_up(s1, d);
            int t2 = __shfl_up(s2, d);
            if (lane >= d) { s0 += t0; s1 += t1; s2 += t2; }
        }
        if (lane == 63) { w0[wid] = s0; w1[wid] = s1; w2[wid] = s2; }
        __syncthreads();
        if (wid == 0 && lane < NWAVES) {        // scan the 16 wave totals
            int a0 = w0[lane], a1 = w1[lane], a2 = w2[lane];
            for (int d = 1; d < NWAVES; d <<= 1) {
                int t0 = __shfl_up(a0, d, NWAVES);
                int t1 = __shfl_up(a1, d, NWAVES);
                int t2 = __shfl_up(a2, d, NWAVES);
                if (lane >= d) { a0 += t0; a1 += t1; a2 += t2; }
            }
            w0[lane] = a0; w1[lane] = a1; w2[lane] = a2;
        }
        __syncthreads();
        int b0 = wid ? w0[wid - 1] : 0;
        int b1 = wid ? w1[wid - 1] : 0;
        int b2 = wid ? w2[wid - 1] : 0;
        int tot0 = w0[NWAVES - 1];
        int tot1 = w1[NWAVES - 1];
        int r0 = b0 + s0 - c0;                  // exclusive prefix, category hi
        int r1 = tot0 + b1 + s1 - c1;           // category mid
        int r2 = tot0 + tot1 + b2 + s2 - c2;    // category 0

        for (int p = p0; p < p1; ++p) {
            unsigned int orig = s_perm[p];
            unsigned char m = s_mask[orig];
            int slot; float samp;
            if (m == hi)       { slot = r0++; samp = (hi == 3) ? 1.0f : -1.0f; }
            else if (m == mid) { slot = r1++; samp = (mid == 3) ? 1.0f : -1.0f; }
            else               { slot = r2++; samp = 0.0f; }
            if (slot < limit) {
                int oslot = oofs + slot;
                float bx0, by0, bx1, by1;
                if (orig < NPROP) {
                    const float* p4 = rois + ((size_t)img * NPROP + orig) * 4;
                    bx0 = p4[0]; by0 = p4[1]; bx1 = p4[2]; by1 = p4[3];
                } else {
                    int g = orig - NPROP;
                    bx0 = s_gt[g * 4 + 0]; by0 = s_gt[g * 4 + 1];
                    bx1 = s_gt[g * 4 + 2]; by1 = s_gt[g * 4 + 3];
                }
                size_t rb = ((size_t)img * NSAMPLE + oslot) * 4;
                out[rb + 0] = bx0; out[rb + 1] = by0;
                out[rb + 2] = bx1; out[rb + 3] = by1;
                out[SAMP_OFF  + (size_t)img * NSAMPLE + oslot] = samp;
                out[MATCH_OFF + (size_t)img * NSAMPLE + oslot] = (float)s_argb[orig];
            }
        }
        __syncthreads();   // w* arrays reused next phase
    }
}

extern "C" void kernel_launch(void* const* d_in, const int* in_sizes, int n_in,
                              void* d_out, int out_size, void* d_ws, size_t ws_size,
                              hipStream_t stream) {
    const float* rois   = (const float*)d_in[0];
    const float* scores = (const float*)d_in[1];
    const float* gts    = (const float*)d_in[2];
    const float* rnd    = (const float*)d_in[3];
    unsigned int* maskarg = (unsigned int*)d_ws;
    unsigned int* rank    = maskarg + (size_t)NIMG * NALL;

    dim3 gridA(NCHUNK, NIMG);
    prep_kernel<<<gridA, 256, 0, stream>>>(rois, scores, gts, rnd, maskarg, rank);
    select_kernel<<<NIMG, CTHREADS, 0, stream>>>(rois, gts, maskarg, rank, (float*)d_out);
}